// Round 1
// baseline (297.107 us; speedup 1.0000x reference)
//
#include <hip/hip_runtime.h>
#include <math.h>

#define BSZ 8
#define NN 20000
#define F_IN 256
#define H 8
#define D 64
#define E 160000

// ---------------------------------------------------------------------------
// Kernel 1: fold W_proj with the per-(b,h) scoring vectors.
//   w_src[b][h][f] = sum_d W_proj[(h*D+d)*F_IN + f] * scoring_src[b,0,h,d]
// Grid: 64 blocks (b*8+h), 256 threads (one per f). Tiny (~1M MACs).
// ---------------------------------------------------------------------------
__global__ __launch_bounds__(256) void fold_weights(
        const float* __restrict__ W_proj,   // [H*D][F_IN]
        const float* __restrict__ s_src,    // [BSZ][1][H][D]
        const float* __restrict__ s_trg,
        float* __restrict__ w_src,          // [BSZ][H][F_IN]
        float* __restrict__ w_trg) {
    __shared__ float ls[D];
    __shared__ float lt[D];
    const int b = blockIdx.x >> 3;
    const int h = blockIdx.x & 7;
    const int f = threadIdx.x;
    if (threadIdx.x < D) {
        ls[threadIdx.x] = s_src[((size_t)b * H + h) * D + threadIdx.x];
        lt[threadIdx.x] = s_trg[((size_t)b * H + h) * D + threadIdx.x];
    }
    __syncthreads();
    float as = 0.f, at = 0.f;
#pragma unroll 8
    for (int d = 0; d < D; ++d) {
        const float wp = W_proj[((size_t)(h * D + d)) * F_IN + f];  // coalesced over f
        as = fmaf(wp, ls[d], as);
        at = fmaf(wp, lt[d], at);
    }
    w_src[((size_t)b * H + h) * F_IN + f] = as;
    w_trg[((size_t)b * H + h) * F_IN + f] = at;
}

// ---------------------------------------------------------------------------
// Kernel 2: per-node, per-head scores (the HBM-bound 164 MB pass).
//   scores_src[b*N*H + n*H + h] = sum_f ch[b][n][f] * w_src[b][h][f]
// Block = 256 threads = 32 nodes x 8 heads. Weights live in LDS (padded rows
// -> conflict-free ds_read_b128); node rows read as global float4 (8 lanes
// share each address -> single request; 64B lines reused across f via L1).
// ---------------------------------------------------------------------------
#define WPAD 260  // 260*4 = 1040 B row stride: 16B-aligned, bank-shifted by 4
__global__ __launch_bounds__(256) void node_scores(
        const float* __restrict__ ch,      // [BSZ][NN][F_IN]
        const float* __restrict__ w_src,   // [BSZ][H][F_IN]
        const float* __restrict__ w_trg,
        float* __restrict__ sc_src,        // [BSZ*NN*H]
        float* __restrict__ sc_trg) {
    __shared__ float lws[H][WPAD];
    __shared__ float lwt[H][WPAD];

    const int bx = blockIdx.x;
    const int b = bx / 625;          // 625 blocks per batch row (625*32 = 20000)
    const int tile = bx % 625;

    // Stage folded weights: 2*8*256 floats, 16 per thread, coalesced.
    const float* gws = w_src + (size_t)b * H * F_IN;
    const float* gwt = w_trg + (size_t)b * H * F_IN;
    for (int i = threadIdx.x; i < H * F_IN; i += 256) {
        lws[i >> 8][i & 255] = gws[i];
        lwt[i >> 8][i & 255] = gwt[i];
    }
    __syncthreads();

    const int h = threadIdx.x & 7;
    const int nl = threadIdx.x >> 3;           // 0..31
    const int n = tile * 32 + nl;              // exact, no tail (20000 = 625*32)

    const float4* __restrict__ chrow = (const float4*)(ch + ((size_t)b * NN + n) * F_IN);
    const float4* __restrict__ wsr = (const float4*)(&lws[h][0]);
    const float4* __restrict__ wtr = (const float4*)(&lwt[h][0]);

    float as = 0.f, at = 0.f;
#pragma unroll 8
    for (int f4 = 0; f4 < F_IN / 4; ++f4) {
        const float4 c = chrow[f4];
        const float4 s = wsr[f4];
        const float4 t = wtr[f4];
        as = fmaf(c.x, s.x, as); as = fmaf(c.y, s.y, as);
        as = fmaf(c.z, s.z, as); as = fmaf(c.w, s.w, as);
        at = fmaf(c.x, t.x, at); at = fmaf(c.y, t.y, at);
        at = fmaf(c.z, t.z, at); at = fmaf(c.w, t.w, at);
    }

    const size_t oi = ((size_t)b * NN + n) * H + h;  // 64 consecutive floats / wave
    sc_src[oi] = as;
    sc_trg[oi] = at;
}

// ---------------------------------------------------------------------------
// Kernel 3: lift (global gather) + sigmoid. Score tables are 5.1 MB each ->
// gathers mostly hit L2/L3.
// ---------------------------------------------------------------------------
__global__ __launch_bounds__(256) void gather_sigmoid(
        const int* __restrict__ head,
        const int* __restrict__ tail,
        const float* __restrict__ sc_src,
        const float* __restrict__ sc_trg,
        float* __restrict__ out, int total) {
    const int i = blockIdx.x * 256 + threadIdx.x;
    if (i < total) {
        const float x = sc_src[head[i]] + sc_trg[tail[i]];
        out[i] = 1.f / (1.f + __expf(-x));
    }
}

extern "C" void kernel_launch(void* const* d_in, const int* in_sizes, int n_in,
                              void* d_out, int out_size, void* d_ws, size_t ws_size,
                              hipStream_t stream) {
    const float* ch   = (const float*)d_in[0];   // [8][20000][256] f32
    const int*   head = (const int*)d_in[1];     // [8][160000] int
    const int*   tail = (const int*)d_in[2];     // [8][160000] int
    const float* W    = (const float*)d_in[3];   // [512][256] f32
    const float* ssrc = (const float*)d_in[4];   // [8][1][8][64] f32
    const float* strg = (const float*)d_in[5];   // [8][1][8][64] f32
    float* out = (float*)d_out;                  // [8][160000] f32

    float* ws = (float*)d_ws;
    float* w_src  = ws;                                   // 16384 floats
    float* w_trg  = ws + BSZ * H * F_IN;                  // 16384 floats
    float* sc_src = ws + 2 * BSZ * H * F_IN;              // 1,280,000 floats
    float* sc_trg = sc_src + (size_t)BSZ * NN * H;        // 1,280,000 floats

    fold_weights<<<BSZ * H, 256, 0, stream>>>(W, ssrc, strg, w_src, w_trg);
    node_scores<<<BSZ * 625, 256, 0, stream>>>(ch, w_src, w_trg, sc_src, sc_trg);
    const int total = BSZ * E;
    gather_sigmoid<<<total / 256, 256, 0, stream>>>(head, tail, sc_src, sc_trg, out, total);
}

// Round 2
// 284.203 us; speedup vs baseline: 1.0454x; 1.0454x over previous
//
#include <hip/hip_runtime.h>
#include <math.h>

#define BSZ 8
#define NN 20000
#define F_IN 256
#define H 8
#define D 64
#define E 160000

// ---------------------------------------------------------------------------
// Kernel 1: fold W_proj with the per-(b,h) scoring vectors.
//   w_src[b][h][f] = sum_d W_proj[(h*D+d)*F_IN + f] * scoring_src[b,0,h,d]
// Grid: 64 blocks (b*8+h), 256 threads (one per f). Tiny (~1M MACs, ~2 us).
// ---------------------------------------------------------------------------
__global__ __launch_bounds__(256) void fold_weights(
        const float* __restrict__ W_proj,   // [H*D][F_IN]
        const float* __restrict__ s_src,    // [BSZ][1][H][D]
        const float* __restrict__ s_trg,
        float* __restrict__ w_src,          // [BSZ][H][F_IN]
        float* __restrict__ w_trg) {
    __shared__ float ls[D];
    __shared__ float lt[D];
    const int b = blockIdx.x >> 3;
    const int h = blockIdx.x & 7;
    const int f = threadIdx.x;
    if (threadIdx.x < D) {
        ls[threadIdx.x] = s_src[((size_t)b * H + h) * D + threadIdx.x];
        lt[threadIdx.x] = s_trg[((size_t)b * H + h) * D + threadIdx.x];
    }
    __syncthreads();
    float as = 0.f, at = 0.f;
#pragma unroll 8
    for (int d = 0; d < D; ++d) {
        const float wp = W_proj[((size_t)(h * D + d)) * F_IN + f];  // coalesced over f
        as = fmaf(wp, ls[d], as);
        at = fmaf(wp, lt[d], at);
    }
    w_src[((size_t)b * H + h) * F_IN + f] = as;
    w_trg[((size_t)b * H + h) * F_IN + f] = at;
}

// ---------------------------------------------------------------------------
// Kernel 2: per-node, per-head scores. HBM-bound: reads ch (164 MB) exactly
// once with fully-coalesced float4 streaming into LDS, computes from LDS.
// Row stride RPAD=260 floats: within a wave the 8 node-groups (stride
// 260*4 B) land on banks (4*g)%32 -> 8 distinct banks, each address
// broadcast to 8 lanes -> conflict-free ds_read_b128.
// LDS: (32 rows + 2*8 weight rows) * 260 * 4 B = 48.75 KB -> 3 blocks/CU.
// ---------------------------------------------------------------------------
#define RPAD 260
__global__ __launch_bounds__(256) void node_scores(
        const float* __restrict__ ch,      // [BSZ][NN][F_IN]
        const float* __restrict__ w_src,   // [BSZ][H][F_IN]
        const float* __restrict__ w_trg,
        float* __restrict__ sc_src,        // [BSZ*NN*H]
        float* __restrict__ sc_trg) {
    __shared__ float lws[H][RPAD];
    __shared__ float lwt[H][RPAD];
    __shared__ float rows[32][RPAD];

    const int bx = blockIdx.x;
    const int b = bx / 625;          // 625 blocks per batch row (625*32 = 20000)
    const int tile = bx % 625;

    // Stage folded weights: 2*8*256 floats, coalesced.
    const float* gws = w_src + (size_t)b * H * F_IN;
    const float* gwt = w_trg + (size_t)b * H * F_IN;
    for (int i = threadIdx.x; i < H * F_IN; i += 256) {
        lws[i >> 8][i & 255] = gws[i];
        lwt[i >> 8][i & 255] = gwt[i];
    }

    // Stage 32 node rows (32 KB) with contiguous 16 B/lane loads.
    const float4* __restrict__ g4 =
        (const float4*)(ch + ((size_t)b * NN + (size_t)tile * 32) * F_IN);
#pragma unroll 8
    for (int i = threadIdx.x; i < 32 * (F_IN / 4); i += 256) {
        const int r = i >> 6;          // node within tile
        const int c = i & 63;          // float4 column
        *((float4*)&rows[r][c * 4]) = g4[i];
    }
    __syncthreads();

    const int h = threadIdx.x & 7;
    const int nl = threadIdx.x >> 3;           // 0..31
    const int n = tile * 32 + nl;              // exact, no tail (20000 = 625*32)

    const float4* __restrict__ crow = (const float4*)(&rows[nl][0]);
    const float4* __restrict__ wsr  = (const float4*)(&lws[h][0]);
    const float4* __restrict__ wtr  = (const float4*)(&lwt[h][0]);

    float as = 0.f, at = 0.f;
#pragma unroll 8
    for (int f4 = 0; f4 < F_IN / 4; ++f4) {
        const float4 c = crow[f4];
        const float4 s = wsr[f4];
        const float4 t = wtr[f4];
        as = fmaf(c.x, s.x, as); as = fmaf(c.y, s.y, as);
        as = fmaf(c.z, s.z, as); as = fmaf(c.w, s.w, as);
        at = fmaf(c.x, t.x, at); at = fmaf(c.y, t.y, at);
        at = fmaf(c.z, t.z, at); at = fmaf(c.w, t.w, at);
    }

    const size_t oi = ((size_t)b * NN + n) * H + h;  // 64 consecutive floats / wave
    sc_src[oi] = as;
    sc_trg[oi] = at;
}

// ---------------------------------------------------------------------------
// Kernel 3: lift (global gather) + sigmoid. 4 edges per thread (int4/float4
// for indices and output); the random score gathers are L2/L3 latency-bound.
// ---------------------------------------------------------------------------
__global__ __launch_bounds__(256) void gather_sigmoid(
        const int4* __restrict__ head4,
        const int4* __restrict__ tail4,
        const float* __restrict__ sc_src,
        const float* __restrict__ sc_trg,
        float4* __restrict__ out4, int total4) {
    const int i = blockIdx.x * 256 + threadIdx.x;
    if (i < total4) {
        const int4 hh = head4[i];
        const int4 tt = tail4[i];
        float4 r;
        r.x = sc_src[hh.x] + sc_trg[tt.x];
        r.y = sc_src[hh.y] + sc_trg[tt.y];
        r.z = sc_src[hh.z] + sc_trg[tt.z];
        r.w = sc_src[hh.w] + sc_trg[tt.w];
        r.x = 1.f / (1.f + __expf(-r.x));
        r.y = 1.f / (1.f + __expf(-r.y));
        r.z = 1.f / (1.f + __expf(-r.z));
        r.w = 1.f / (1.f + __expf(-r.w));
        out4[i] = r;
    }
}

extern "C" void kernel_launch(void* const* d_in, const int* in_sizes, int n_in,
                              void* d_out, int out_size, void* d_ws, size_t ws_size,
                              hipStream_t stream) {
    const float* ch   = (const float*)d_in[0];   // [8][20000][256] f32
    const int*   head = (const int*)d_in[1];     // [8][160000] int
    const int*   tail = (const int*)d_in[2];     // [8][160000] int
    const float* W    = (const float*)d_in[3];   // [512][256] f32
    const float* ssrc = (const float*)d_in[4];   // [8][1][8][64] f32
    const float* strg = (const float*)d_in[5];   // [8][1][8][64] f32
    float* out = (float*)d_out;                  // [8][160000] f32

    float* ws = (float*)d_ws;
    float* w_src  = ws;                                   // 16384 floats
    float* w_trg  = ws + BSZ * H * F_IN;                  // 16384 floats
    float* sc_src = ws + 2 * BSZ * H * F_IN;              // 1,280,000 floats
    float* sc_trg = sc_src + (size_t)BSZ * NN * H;        // 1,280,000 floats

    fold_weights<<<BSZ * H, 256, 0, stream>>>(W, ssrc, strg, w_src, w_trg);
    node_scores<<<BSZ * 625, 256, 0, stream>>>(ch, w_src, w_trg, sc_src, sc_trg);
    const int total4 = (BSZ * E) / 4;                     // 320000
    gather_sigmoid<<<(total4 + 255) / 256, 256, 0, stream>>>(
        (const int4*)head, (const int4*)tail, sc_src, sc_trg, (float4*)out, total4);
}

// Round 4
// 276.732 us; speedup vs baseline: 1.0736x; 1.0270x over previous
//
#include <hip/hip_runtime.h>
#include <math.h>

#define BSZ 8
#define NN 20000
#define F_IN 256
#define H 8
#define D 64
#define E 160000

typedef _Float16 half_t;
typedef float  fx4 __attribute__((ext_vector_type(4)));
typedef int    ix4 __attribute__((ext_vector_type(4)));

// ---------------------------------------------------------------------------
// Kernel 1: fold W_proj with the per-(b,h) scoring vectors.
//   w_src[b][h][f] = sum_d W_proj[(h*D+d)*F_IN + f] * scoring_src[b,0,h,d]
// Grid: 64 blocks (b*8+h), 256 threads (one per f). Tiny (~1M MACs, ~3 us).
// ---------------------------------------------------------------------------
__global__ __launch_bounds__(256) void fold_weights(
        const float* __restrict__ W_proj,   // [H*D][F_IN]
        const float* __restrict__ s_src,    // [BSZ][1][H][D]
        const float* __restrict__ s_trg,
        float* __restrict__ w_src,          // [BSZ][H][F_IN]
        float* __restrict__ w_trg) {
    __shared__ float ls[D];
    __shared__ float lt[D];
    const int b = blockIdx.x >> 3;
    const int h = blockIdx.x & 7;
    const int f = threadIdx.x;
    if (threadIdx.x < D) {
        ls[threadIdx.x] = s_src[((size_t)b * H + h) * D + threadIdx.x];
        lt[threadIdx.x] = s_trg[((size_t)b * H + h) * D + threadIdx.x];
    }
    __syncthreads();
    float as = 0.f, at = 0.f;
#pragma unroll 8
    for (int d = 0; d < D; ++d) {
        const float wp = W_proj[((size_t)(h * D + d)) * F_IN + f];  // coalesced over f
        as = fmaf(wp, ls[d], as);
        at = fmaf(wp, lt[d], at);
    }
    w_src[((size_t)b * H + h) * F_IN + f] = as;
    w_trg[((size_t)b * H + h) * F_IN + f] = at;
}

// ---------------------------------------------------------------------------
// Kernel 2: per-node, per-head scores. HBM-bound: streams ch (164 MB) exactly
// once (non-temporal fx4 -> LDS), computes from LDS, writes fp16 scores
// (5.1 MB total). Row stride RPAD=260 floats keeps ds_read_b128 conflict-free
// (8 node-groups land on 8 distinct banks, each broadcast to 8 lanes).
// LDS: (32 + 16) * 260 * 4 B = 48.75 KB -> 3 blocks/CU.
// ---------------------------------------------------------------------------
#define RPAD 260
__global__ __launch_bounds__(256) void node_scores(
        const float* __restrict__ ch,      // [BSZ][NN][F_IN]
        const float* __restrict__ w_src,   // [BSZ][H][F_IN]
        const float* __restrict__ w_trg,
        half_t* __restrict__ sc_src,       // [BSZ*NN*H] fp16
        half_t* __restrict__ sc_trg) {
    __shared__ float lws[H][RPAD];
    __shared__ float lwt[H][RPAD];
    __shared__ float rows[32][RPAD];

    const int bx = blockIdx.x;
    const int b = bx / 625;          // 625 blocks per batch row (625*32 = 20000)
    const int tile = bx % 625;

    // Stage folded weights: 2*8*256 floats, coalesced.
    const float* gws = w_src + (size_t)b * H * F_IN;
    const float* gwt = w_trg + (size_t)b * H * F_IN;
    for (int i = threadIdx.x; i < H * F_IN; i += 256) {
        lws[i >> 8][i & 255] = gws[i];
        lwt[i >> 8][i & 255] = gwt[i];
    }

    // Stage 32 node rows (32 KB), non-temporal contiguous 16 B/lane loads.
    const fx4* __restrict__ g4 =
        (const fx4*)(ch + ((size_t)b * NN + (size_t)tile * 32) * F_IN);
#pragma unroll 8
    for (int i = threadIdx.x; i < 32 * (F_IN / 4); i += 256) {
        const int r = i >> 6;          // node within tile
        const int c = i & 63;          // float4 column
        *((fx4*)&rows[r][c * 4]) = __builtin_nontemporal_load(&g4[i]);
    }
    __syncthreads();

    const int h = threadIdx.x & 7;
    const int nl = threadIdx.x >> 3;           // 0..31
    const int n = tile * 32 + nl;              // exact, no tail (20000 = 625*32)

    const fx4* __restrict__ crow = (const fx4*)(&rows[nl][0]);
    const fx4* __restrict__ wsr  = (const fx4*)(&lws[h][0]);
    const fx4* __restrict__ wtr  = (const fx4*)(&lwt[h][0]);

    float as = 0.f, at = 0.f;
#pragma unroll 8
    for (int f4 = 0; f4 < F_IN / 4; ++f4) {
        const fx4 c = crow[f4];
        const fx4 s = wsr[f4];
        const fx4 t = wtr[f4];
        as = fmaf(c.x, s.x, as); as = fmaf(c.y, s.y, as);
        as = fmaf(c.z, s.z, as); as = fmaf(c.w, s.w, as);
        at = fmaf(c.x, t.x, at); at = fmaf(c.y, t.y, at);
        at = fmaf(c.z, t.z, at); at = fmaf(c.w, t.w, at);
    }

    const size_t oi = ((size_t)b * NN + n) * H + h;  // 64 consecutive halves / wave
    sc_src[oi] = (half_t)as;
    sc_trg[oi] = (half_t)at;
}

// ---------------------------------------------------------------------------
// Kernel 3: lift (global gather) + sigmoid. 4 edges per thread. Indices and
// output are streamed non-temporally so the fp16 score tables (5.1 MB total)
// stay resident in L2/L3 for the random gathers.
// ---------------------------------------------------------------------------
__global__ __launch_bounds__(256) void gather_sigmoid(
        const ix4* __restrict__ head4,
        const ix4* __restrict__ tail4,
        const half_t* __restrict__ sc_src,
        const half_t* __restrict__ sc_trg,
        fx4* __restrict__ out4, int total4) {
    const int i = blockIdx.x * 256 + threadIdx.x;
    if (i < total4) {
        const ix4 hh = __builtin_nontemporal_load(&head4[i]);
        const ix4 tt = __builtin_nontemporal_load(&tail4[i]);
        fx4 r;
        r.x = (float)sc_src[hh.x] + (float)sc_trg[tt.x];
        r.y = (float)sc_src[hh.y] + (float)sc_trg[tt.y];
        r.z = (float)sc_src[hh.z] + (float)sc_trg[tt.z];
        r.w = (float)sc_src[hh.w] + (float)sc_trg[tt.w];
        r.x = 1.f / (1.f + __expf(-r.x));
        r.y = 1.f / (1.f + __expf(-r.y));
        r.z = 1.f / (1.f + __expf(-r.z));
        r.w = 1.f / (1.f + __expf(-r.w));
        __builtin_nontemporal_store(r, &out4[i]);
    }
}

extern "C" void kernel_launch(void* const* d_in, const int* in_sizes, int n_in,
                              void* d_out, int out_size, void* d_ws, size_t ws_size,
                              hipStream_t stream) {
    const float* ch   = (const float*)d_in[0];   // [8][20000][256] f32
    const int*   head = (const int*)d_in[1];     // [8][160000] int
    const int*   tail = (const int*)d_in[2];     // [8][160000] int
    const float* W    = (const float*)d_in[3];   // [512][256] f32
    const float* ssrc = (const float*)d_in[4];   // [8][1][8][64] f32
    const float* strg = (const float*)d_in[5];   // [8][1][8][64] f32
    float* out = (float*)d_out;                  // [8][160000] f32

    float* ws = (float*)d_ws;
    float* w_src  = ws;                                   // 16384 floats
    float* w_trg  = ws + BSZ * H * F_IN;                  // 16384 floats
    half_t* sc_src = (half_t*)(ws + 2 * BSZ * H * F_IN);  // 1,280,000 halves
    half_t* sc_trg = sc_src + (size_t)BSZ * NN * H;       // 1,280,000 halves

    fold_weights<<<BSZ * H, 256, 0, stream>>>(W, ssrc, strg, w_src, w_trg);
    node_scores<<<BSZ * 625, 256, 0, stream>>>(ch, w_src, w_trg, sc_src, sc_trg);
    const int total4 = (BSZ * E) / 4;                     // 320000
    gather_sigmoid<<<(total4 + 255) / 256, 256, 0, stream>>>(
        (const ix4*)head, (const ix4*)tail, sc_src, sc_trg, (fx4*)out, total4);
}